// Round 2
// baseline (1451.032 us; speedup 1.0000x reference)
//
#include <hip/hip_runtime.h>

#define BB    32
#define CDIM  256
#define TT    2048
#define NE    1024
#define NROWS (BB * TT)          // 65536
#define NELEM (BB * CDIM * TT)   // 16777216

// dist_argmin tiling
#define RT 128                   // rows per block
#define CT 128                   // codes per chunk
#define KC 32                    // k's per LDS stage
#define NHALF 512                // codes per block (code-split factor 2)
#define ESTRIDE 132              // es row stride (write-conflict pad)

// screening window: |d_approx - d_exact| <= B ~ 3.2e-5 (ulp(256) subtract
// quantization + fma-vs-muladd drift).  W must be > 2B; rows with
// (2nd best - best) <= W are re-resolved by the bit-exact fallback scan.
#define FBW 2.0e-4f

typedef float v2f __attribute__((ext_vector_type(2)));

// v_pk_fma_f32 with op_sel broadcasting one half of Z to both lanes:
//   LO: res = { Z.lo*E.lo + A.lo , Z.lo*E.hi + A.hi }
//   HI: res = { Z.hi*E.lo + A.lo , Z.hi*E.hi + A.hi }
#define PK_FMA_LO(A, Z, E)                                                   \
  asm("v_pk_fma_f32 %0, %1, %2, %0 op_sel:[0,0,0] op_sel_hi:[0,1,1]"         \
      : "+v"(A) : "v"(Z), "v"(E))
#define PK_FMA_HI(A, Z, E)                                                   \
  asm("v_pk_fma_f32 %0, %1, %2, %0 op_sel:[1,0,0] op_sel_hi:[1,1,1]"         \
      : "+v"(A) : "v"(Z), "v"(E))

// ---------------------------------------------------------------------------
// numpy pairwise sum of squares over 128 elements (stride in elements).
// fp contract OFF (numpy squares then adds, no FMA).
// ---------------------------------------------------------------------------
__device__ __forceinline__ float np_sq_sum128(const float* p, int stride) {
#pragma clang fp contract(off)
  float r[8];
#pragma unroll
  for (int j = 0; j < 8; j++) {
    float v = p[(size_t)j * stride];
    r[j] = v * v;
  }
  for (int i = 8; i < 128; i += 8) {
#pragma unroll
    for (int j = 0; j < 8; j++) {
      float v = p[(size_t)(i + j) * stride];
      float s = v * v;
      r[j] += s;
    }
  }
  return ((r[0] + r[1]) + (r[2] + r[3])) + ((r[4] + r[5]) + (r[6] + r[7]));
}

__global__ __launch_bounds__(256) void e2_kernel(const float* __restrict__ cb,
                                                 float* __restrict__ e2) {
#pragma clang fp contract(off)
  int k = blockIdx.x * 256 + threadIdx.x;
  if (k >= NE) return;
  const float* p = cb + (size_t)k * CDIM;
  float h0 = np_sq_sum128(p, 1);
  float h1 = np_sq_sum128(p + 128, 1);
  e2[k] = h0 + h1;
}

__global__ __launch_bounds__(256) void z2_kernel(const float* __restrict__ z,
                                                 float* __restrict__ z2) {
#pragma clang fp contract(off)
  int n = blockIdx.x * 256 + threadIdx.x;
  if (n >= NROWS) return;
  int b = n >> 11;
  int t = n & (TT - 1);
  const float* p = z + (size_t)b * CDIM * TT + t;
  float h0 = np_sq_sum128(p, TT);
  float h1 = np_sq_sum128(p + (size_t)128 * TT, TT);
  z2[n] = h0 + h1;
}

// cb (1024 x 256) -> cbT (256 x 1024), both reads and writes coalesced
__global__ __launch_bounds__(256) void transpose_cb_kernel(
    const float* __restrict__ cb, float* __restrict__ cbT) {
  __shared__ float tile[32][33];
  int tx = threadIdx.x & 31, ty = threadIdx.x >> 5;
  int n0 = blockIdx.x * 32, c0 = blockIdx.y * 32;
#pragma unroll
  for (int i = 0; i < 4; i++)
    tile[ty + 8 * i][tx] = cb[(size_t)(n0 + ty + 8 * i) * CDIM + c0 + tx];
  __syncthreads();
#pragma unroll
  for (int i = 0; i < 4; i++)
    cbT[(size_t)(c0 + ty + 8 * i) * NE + n0 + tx] = tile[tx][ty + 8 * i];
}

// ---------------------------------------------------------------------------
// Distance + argmin, v5: FMA *screening* pass (v_pk_fma_f32 via inline asm,
// op_sel row-broadcast) + per-row best-2 tracking.  Rows whose top-2 approx
// distances are within FBW are re-resolved bit-exactly by fallback_kernel.
// Codebook staged from pre-transposed cbT (coalesced float4 loads).
// Block: 128 rows x 512 codes, 256 threads (16 tx x 16 ty), 8x8 accs.
// ---------------------------------------------------------------------------
struct StageMem {
  float zs[KC][RT];              // 16 KiB  [k][row]
  float es[KC][ESTRIDE];         // 16.5 KiB [k][code]
};
struct RedMem {
  float rv1[RT][17];
  float rv2[RT][17];
  int   ri1[RT][17];
};

__global__ __launch_bounds__(256, 4) void dist_argmin_kernel(
    const float* __restrict__ z, const float* __restrict__ cbT,
    const float* __restrict__ z2, const float* __restrict__ e2,
    float* __restrict__ pv1, float* __restrict__ pv2,
    int* __restrict__ pi1) {
#pragma clang fp contract(off)
  __shared__ union SMem {
    StageMem st;
    RedMem   rd;
  } sm;

  const int bid  = blockIdx.x;
  const int half = bid & 1;               // code half
  const int rt   = bid >> 1;              // row tile 0..511
  const int b    = rt >> 4;
  const int t0   = (rt & 15) << 7;
  const int n_base = half * NHALF;
  const int tid = threadIdx.x;
  const int tx  = tid & 15;               // code group
  const int ty  = tid >> 4;               // row group

  const float* zb = z + (size_t)b * CDIM * TT + t0;

  // staging coordinates: 32 quads x 8 k-groups
  const int c4 = tid & 31;
  const int kq = tid >> 5;

  float bv1[8], bv2[8];
  int   bi1[8];
#pragma unroll
  for (int r = 0; r < 8; r++) {
    bv1[r] = __builtin_inff(); bv2[r] = __builtin_inff(); bi1[r] = 0;
  }

  float z2r[8];
#pragma unroll
  for (int r = 0; r < 8; r++) {
    int row = (r < 4) ? (ty * 4 + r) : (64 + ty * 4 + (r - 4));
    z2r[r] = z2[b * TT + t0 + row];
  }

  for (int n0 = n_base; n0 < n_base + NHALF; n0 += CT) {
    v2f acc2[8][4];
#pragma unroll
    for (int r = 0; r < 8; r++)
#pragma unroll
      for (int j = 0; j < 4; j++) acc2[r][j] = (v2f){0.0f, 0.0f};

    for (int kc = 0; kc < CDIM; kc += KC) {
      __syncthreads();
      // stage z: 32 k x 128 t, float4 in / b128 out
#pragma unroll
      for (int h = 0; h < 4; h++) {
        int k = kq + 8 * h;
        float4 v = *(const float4*)(zb + (size_t)(kc + k) * TT + c4 * 4);
        *(float4*)&sm.st.zs[k][c4 * 4] = v;
      }
      // stage cb from cbT: 32 k x 128 codes, coalesced float4 loads
#pragma unroll
      for (int h = 0; h < 4; h++) {
        int k = kq + 8 * h;
        float4 v = *(const float4*)(cbT + (size_t)(kc + k) * NE + n0 + c4 * 4);
        *(float4*)&sm.st.es[k][c4 * 4] = v;
      }
      __syncthreads();

#pragma unroll 4
      for (int k = 0; k < KC; k++) {
        float4 zA = *(const float4*)&sm.st.zs[k][ty * 4];
        float4 zB = *(const float4*)&sm.st.zs[k][64 + ty * 4];
        float4 e0 = *(const float4*)&sm.st.es[k][tx * 4];
        float4 e1 = *(const float4*)&sm.st.es[k][64 + tx * 4];
        v2f zp[4], ep[4];
        zp[0] = (v2f){zA.x, zA.y}; zp[1] = (v2f){zA.z, zA.w};
        zp[2] = (v2f){zB.x, zB.y}; zp[3] = (v2f){zB.z, zB.w};
        ep[0] = (v2f){e0.x, e0.y}; ep[1] = (v2f){e0.z, e0.w};
        ep[2] = (v2f){e1.x, e1.y}; ep[3] = (v2f){e1.z, e1.w};
#pragma unroll
        for (int rp = 0; rp < 4; rp++) {
#pragma unroll
          for (int j = 0; j < 4; j++) {
            PK_FMA_LO(acc2[2 * rp + 0][j], zp[rp], ep[j]);
            PK_FMA_HI(acc2[2 * rp + 1][j], zp[rp], ep[j]);
          }
        }
      }
    }

    // chunk epilogue: approx d, fold into running best-2
    float e2c[8]; int codes[8];
#pragma unroll
    for (int j = 0; j < 8; j++) {
      codes[j] = n0 + ((j < 4) ? (tx * 4 + j) : (64 + tx * 4 + (j - 4)));
      e2c[j]   = e2[codes[j]];
    }
#pragma unroll
    for (int r = 0; r < 8; r++) {
#pragma unroll
      for (int j = 0; j < 8; j++) {
        float a = acc2[r][j >> 1][j & 1];
        float d = (z2r[r] + e2c[j]) - 2.0f * a;
        if (d < bv2[r]) {
          if (d < bv1[r]) { bv2[r] = bv1[r]; bv1[r] = d; bi1[r] = codes[j]; }
          else bv2[r] = d;
        }
      }
    }
  }

  __syncthreads();
#pragma unroll
  for (int r = 0; r < 8; r++) {
    int row = (r < 4) ? (ty * 4 + r) : (64 + ty * 4 + (r - 4));
    sm.rd.rv1[row][tx] = bv1[r];
    sm.rd.rv2[row][tx] = bv2[r];
    sm.rd.ri1[row][tx] = bi1[r];
  }
  __syncthreads();
  if (tid < RT) {
    float v1 = sm.rd.rv1[tid][0];
    float v2 = sm.rd.rv2[tid][0];
    int   i1 = sm.rd.ri1[tid][0];
#pragma unroll
    for (int x = 1; x < 16; x++) {
      float a1 = sm.rd.rv1[tid][x];
      float a2 = sm.rd.rv2[tid][x];
      int   ai = sm.rd.ri1[tid][x];
      if (a1 < v1 || (a1 == v1 && ai < i1)) {
        v2 = fminf(v1, a2); v1 = a1; i1 = ai;
      } else {
        v2 = fminf(v2, a1);
      }
    }
    int row = b * TT + t0 + tid;
    pv1[half * NROWS + row] = v1;
    pv2[half * NROWS + row] = v2;
    pi1[half * NROWS + row] = i1;
  }
}

// combine halves' best-2; flag rows whose top-2 are within the window
__global__ __launch_bounds__(256) void combine_kernel(
    const float* __restrict__ pv1, const float* __restrict__ pv2,
    const int* __restrict__ pi1, int* __restrict__ out_idx,
    int* __restrict__ fb_cnt, int* __restrict__ fb_list) {
  int n = blockIdx.x * 256 + threadIdx.x;
  if (n >= NROWS) return;
  float a1 = pv1[n], b1 = pv1[NROWS + n];
  float a2 = pv2[n], b2 = pv2[NROWS + n];
  int   ai = pi1[n], bi = pi1[NROWS + n];
  float g1, gsec; int gi;
  if (b1 < a1) { g1 = b1; gi = bi; gsec = fminf(a1, b2); }
  else         { g1 = a1; gi = ai; gsec = fminf(b1, a2); }  // ties: half0 wins
  out_idx[n] = gi;
  if (gsec - g1 <= FBW) fb_list[atomicAdd(fb_cnt, 1)] = n;
}

// bit-exact (numpy semantics) full rescan for flagged rows
__global__ __launch_bounds__(256) void fallback_kernel(
    const float* __restrict__ z, const float* __restrict__ cb,
    const float* __restrict__ z2, const float* __restrict__ e2,
    const int* __restrict__ fb_cnt, const int* __restrict__ fb_list,
    int* __restrict__ out_idx) {
#pragma clang fp contract(off)
  __shared__ float zrow[CDIM];
  __shared__ float rv[256];
  __shared__ int   ri[256];
  int cnt = *fb_cnt;
  int tid = threadIdx.x;
  for (int q = blockIdx.x; q < cnt; q += gridDim.x) {
    int n = fb_list[q];
    int b = n >> 11, t = n & (TT - 1);
    zrow[tid] = z[(size_t)b * CDIM * TT + (size_t)tid * TT + t];
    __syncthreads();
    float z2n = z2[n];
    const float* cr = cb + (size_t)(tid * 4) * CDIM;
    float acc[4] = {0.f, 0.f, 0.f, 0.f};
    for (int k = 0; k < CDIM; k++) {
      float zk = zrow[k];
      acc[0] = acc[0] + zk * cr[k];
      acc[1] = acc[1] + zk * cr[CDIM + k];
      acc[2] = acc[2] + zk * cr[2 * CDIM + k];
      acc[3] = acc[3] + zk * cr[3 * CDIM + k];
    }
    float bv = __builtin_inff(); int bi = 0;
#pragma unroll
    for (int j = 0; j < 4; j++) {
      int   code = tid * 4 + j;
      float d    = (z2n + e2[code]) - 2.0f * acc[j];
      if (d < bv) { bv = d; bi = code; }
    }
    rv[tid] = bv; ri[tid] = bi;
    __syncthreads();
    for (int s = 128; s > 0; s >>= 1) {
      if (tid < s) {
        float v2v = rv[tid + s]; int i2v = ri[tid + s];
        if (v2v < rv[tid] || (v2v == rv[tid] && i2v < ri[tid])) {
          rv[tid] = v2v; ri[tid] = i2v;
        }
      }
      __syncthreads();
    }
    if (tid == 0) out_idx[n] = ri[0];
    __syncthreads();
  }
}

// ---------------------------------------------------------------------------
// Gather z_q, straight-through output fl(z + fl(zq - z)), loss accumulation
// ---------------------------------------------------------------------------
__global__ __launch_bounds__(256) void zq_loss_kernel(
    const float* __restrict__ z, const float* __restrict__ cb,
    const int* __restrict__ idx, float* __restrict__ zq_out,
    double* __restrict__ loss_acc) {
#pragma clang fp contract(off)
  __shared__ double sh[256];
  double local = 0.0;
  int stride = gridDim.x * blockDim.x;
  for (int i = blockIdx.x * blockDim.x + threadIdx.x; i < NELEM; i += stride) {
    int t = i & (TT - 1);
    int b = i >> 19;
    int c = (i >> 11) & (CDIM - 1);
    int n = (b << 11) | t;
    float zq   = cb[(size_t)idx[n] * CDIM + c];
    float zv   = z[i];
    float diff = zq - zv;
    zq_out[i]  = zv + diff;
    float sq   = diff * diff;
    local += (double)sq;
  }
  sh[threadIdx.x] = local;
  __syncthreads();
  for (int s = 128; s > 0; s >>= 1) {
    if (threadIdx.x < s) sh[threadIdx.x] += sh[threadIdx.x + s];
    __syncthreads();
  }
  if (threadIdx.x == 0) atomicAdd(loss_acc, sh[0]);
}

// one-hot (every element written once) + indices output + histogram
__global__ __launch_bounds__(256) void onehot_kernel(
    const int* __restrict__ idx, float* __restrict__ oh,
    float* __restrict__ idx_out, int* __restrict__ cnt) {
  int row  = blockIdx.x * 4 + (threadIdx.x >> 6);
  int lane = threadIdx.x & 63;
  int k    = idx[row];
  if (lane == 0) {
    idx_out[row] = (float)k;
    atomicAdd(&cnt[k], 1);
  }
  float4* dst = (float4*)(oh + (size_t)row * NE);
#pragma unroll
  for (int i = 0; i < 4; i++) {
    int c4   = i * 64 + lane;
    int base = c4 * 4;
    float4 v = {0.f, 0.f, 0.f, 0.f};
    if (k >= base && k < base + 4) ((float*)&v)[k - base] = 1.0f;
    dst[c4] = v;
  }
}

__global__ __launch_bounds__(1024) void finalize_kernel(
    const int* __restrict__ cnt, const double* __restrict__ loss_acc,
    float* __restrict__ out_loss, float* __restrict__ out_perp) {
#pragma clang fp contract(off)
  __shared__ float sh[1024];
  int t = threadIdx.x;
  float em = (float)cnt[t] / 65536.0f;
  sh[t] = em * logf(em + 1e-10f);
  __syncthreads();
  for (int s = 512; s > 0; s >>= 1) {
    if (t < s) sh[t] += sh[t + s];
    __syncthreads();
  }
  if (t == 0) {
    *out_perp = expf(-sh[0]);
    double m  = *loss_acc / (double)NELEM;
    float mf  = (float)m;
    float bt  = 0.25f * mf;
    *out_loss = mf + bt;
  }
}

// ---------------------------------------------------------------------------
extern "C" void kernel_launch(void* const* d_in, const int* in_sizes, int n_in,
                              void* d_out, int out_size, void* d_ws,
                              size_t ws_size, hipStream_t stream) {
  const float* z  = (const float*)d_in[0];
  const float* cb = (const float*)d_in[1];
  float* out = (float*)d_out;

  // workspace layout
  int*    ws_idx   = (int*)d_ws;                 // 65536 ints
  int*    ws_cnt   = ws_idx + NROWS;             // 1024 ints
  int*    ws_fbcnt = ws_cnt + NE;                // 1 int
  int*    ws_pad   = ws_fbcnt + 1;               // 1 int (align)
  double* ws_loss  = (double*)(ws_pad + 1);      // 1 double
  float*  ws_e2    = (float*)(ws_loss + 1);      // 1024 floats
  float*  ws_z2    = ws_e2 + NE;                 // 65536 floats
  float*  ws_pv1   = ws_z2 + NROWS;              // 2*65536 floats
  float*  ws_pv2   = ws_pv1 + 2 * NROWS;         // 2*65536 floats
  int*    ws_pi1   = (int*)(ws_pv2 + 2 * NROWS); // 2*65536 ints
  int*    ws_fbl   = ws_pi1 + 2 * NROWS;         // 65536 ints
  float*  ws_cbT   = (float*)(ws_fbl + NROWS);   // 256*1024 floats (16B-aligned)

  // output layout (flat fp32 concat, reference return order)
  float* out_loss = out;
  float* out_zq   = out + 1;
  float* out_perp = out + 1 + (size_t)NELEM;
  float* out_oh   = out + 2 + (size_t)NELEM;
  float* out_idx  = out + 2 + (size_t)NELEM + (size_t)NROWS * NE;

  // zero cnt + fbcnt + pad + loss in one shot (contiguous)
  hipMemsetAsync(ws_cnt, 0, NE * sizeof(int) + 2 * sizeof(int) + sizeof(double),
                 stream);

  transpose_cb_kernel<<<dim3(NE / 32, CDIM / 32), 256, 0, stream>>>(cb, ws_cbT);
  e2_kernel<<<NE / 256, 256, 0, stream>>>(cb, ws_e2);
  z2_kernel<<<NROWS / 256, 256, 0, stream>>>(z, ws_z2);
  dist_argmin_kernel<<<(NROWS / RT) * 2, 256, 0, stream>>>(
      z, ws_cbT, ws_z2, ws_e2, ws_pv1, ws_pv2, ws_pi1);
  combine_kernel<<<NROWS / 256, 256, 0, stream>>>(ws_pv1, ws_pv2, ws_pi1,
                                                  ws_idx, ws_fbcnt, ws_fbl);
  fallback_kernel<<<512, 256, 0, stream>>>(z, cb, ws_z2, ws_e2, ws_fbcnt,
                                           ws_fbl, ws_idx);
  zq_loss_kernel<<<2048, 256, 0, stream>>>(z, cb, ws_idx, out_zq, ws_loss);
  onehot_kernel<<<NROWS / 4, 256, 0, stream>>>(ws_idx, out_oh, out_idx,
                                               ws_cnt);
  finalize_kernel<<<1, 1024, 0, stream>>>(ws_cnt, ws_loss, out_loss, out_perp);
}

// Round 3
// 1266.140 us; speedup vs baseline: 1.1460x; 1.1460x over previous
//
#include <hip/hip_runtime.h>

#define BB    32
#define CDIM  256
#define TT    2048
#define NE    1024
#define NROWS (BB * TT)          // 65536
#define NELEM (BB * CDIM * TT)   // 16777216

#define BM   128                 // rows per block
#define NCH  8                   // code chunks of 128 (all 1024 codes/block)

// screening window: |d_scr + z2 - d_exact| <= B ~ 8e-5 hard
// (split residuals 1.6e-5 + fp32-order diff ~3e-5 + ulp(256)=3.05e-5).
// FBW > 2B; rows with (2nd best - best) <= FBW go to bit-exact fallback.
#define FBW 2.5e-4f

typedef unsigned short u16;
typedef unsigned int   u32;
typedef __attribute__((ext_vector_type(8))) short s16x8;   // 8 bf16
typedef __attribute__((ext_vector_type(4))) float f32x4;

__device__ __forceinline__ u16 f2bf(float f) {
  u32 u = __float_as_uint(f);
  u += 0x7fffu + ((u >> 16) & 1u);     // RNE; no NaN/overflow in our range
  return (u16)(u >> 16);
}

// ---------------------------------------------------------------------------
// numpy pairwise sum of squares over 128 elements (stride in elements).
// fp contract OFF (numpy squares then adds, no FMA).  EXACT path helpers.
// ---------------------------------------------------------------------------
__device__ __forceinline__ float np_sq_sum128(const float* p, int stride) {
#pragma clang fp contract(off)
  float r[8];
#pragma unroll
  for (int j = 0; j < 8; j++) {
    float v = p[(size_t)j * stride];
    r[j] = v * v;
  }
  for (int i = 8; i < 128; i += 8) {
#pragma unroll
    for (int j = 0; j < 8; j++) {
      float v = p[(size_t)(i + j) * stride];
      float s = v * v;
      r[j] += s;
    }
  }
  return ((r[0] + r[1]) + (r[2] + r[3])) + ((r[4] + r[5]) + (r[6] + r[7]));
}

__global__ __launch_bounds__(256) void e2_kernel(const float* __restrict__ cb,
                                                 float* __restrict__ e2) {
#pragma clang fp contract(off)
  int k = blockIdx.x * 256 + threadIdx.x;
  if (k >= NE) return;
  const float* p = cb + (size_t)k * CDIM;
  float h0 = np_sq_sum128(p, 1);
  float h1 = np_sq_sum128(p + 128, 1);
  e2[k] = h0 + h1;
}

__global__ __launch_bounds__(256) void z2_kernel(const float* __restrict__ z,
                                                 float* __restrict__ z2) {
#pragma clang fp contract(off)
  int n = blockIdx.x * 256 + threadIdx.x;
  if (n >= NROWS) return;
  int b = n >> 11;
  int t = n & (TT - 1);
  const float* p = z + (size_t)b * CDIM * TT + t;
  float h0 = np_sq_sum128(p, TT);
  float h1 = np_sq_sum128(p + (size_t)128 * TT, TT);
  z2[n] = h0 + h1;
}

// ---------------------------------------------------------------------------
// cb (1024 x 256) fp32 -> cbhi/cblo bf16 (hi + residual), same [code][k] layout
// ---------------------------------------------------------------------------
__global__ __launch_bounds__(256) void convert_cb_kernel(
    const float* __restrict__ cb, u16* __restrict__ cbhi,
    u16* __restrict__ cblo) {
  int i = blockIdx.x * 256 + threadIdx.x;   // grid 1024 -> 262144 elems
  float v  = cb[i];
  u16  h   = f2bf(v);
  float hf = __uint_as_float((u32)h << 16);
  cbhi[i] = h;
  cblo[i] = f2bf(v - hf);
}

// ---------------------------------------------------------------------------
// z (B, C, T) fp32 -> zhi/zlo bf16 row-major [(b,t)][c]   (tiled transpose)
// ---------------------------------------------------------------------------
__global__ __launch_bounds__(256) void convert_z_kernel(
    const float* __restrict__ z, u16* __restrict__ zhi,
    u16* __restrict__ zlo) {
  __shared__ float tile[32][33];
  int bx = blockIdx.x;              // 32 b * 8 c-tiles * 64 t-tiles = 16384
  int b  = bx >> 9;
  int r  = bx & 511;
  int c0 = (r >> 6) << 5;
  int t0 = (r & 63) << 5;
  int tx = threadIdx.x & 31, ty = threadIdx.x >> 5;
#pragma unroll
  for (int i = 0; i < 4; i++) {
    int c = c0 + ty + 8 * i;
    tile[ty + 8 * i][tx] = z[((size_t)b * CDIM + c) * TT + t0 + tx];
  }
  __syncthreads();
#pragma unroll
  for (int i = 0; i < 4; i++) {
    int tl = ty + 8 * i;
    size_t n = (size_t)b * TT + t0 + tl;
    float v  = tile[tx][tl];
    u16  h   = f2bf(v);
    float hf = __uint_as_float((u32)h << 16);
    zhi[n * CDIM + c0 + tx] = h;
    zlo[n * CDIM + c0 + tx] = f2bf(v - hf);
  }
}

// ---------------------------------------------------------------------------
// Distance screen + argmin, v6: bf16-split MFMA GEMM.
// G = zhi*chi + zhi*clo + zlo*chi (3 chained 16x16x32 bf16 MFMAs, fp32 acc).
// Screened d = e2[c] - 2G (z2 is per-row constant: argmin/gap invariant).
// Per block: 128 rows x all 1024 codes (8 chunks of 128), K=256 in 4 phases
// of 64 (two 32-k planes).  4 waves as 2x2 (wave tile 64 rows x 64 codes,
// 4x4 MFMA tiles).  global_load_lds staging with XOR-swizzled source so the
// per-lane frag ds_read_b128 is 2-way-conflict-free (T21: both-sides swizzle).
// Lane-local running best-2 per row-slot; butterfly merge at end; rows with
// gap <= FBW flagged for the bit-exact fallback.
// ---------------------------------------------------------------------------
struct StageMem {                       // 64 KiB
  u16 ah[2][128][32];                   // zhi  [plane][row][k]
  u16 al[2][128][32];                   // zlo
  u16 bh[2][128][32];                   // cbhi [plane][code][k]
  u16 bl[2][128][32];                   // cblo
};
struct RedMem {
  float rv1[BM][2];
  float rv2[BM][2];
  int   ri1[BM][2];
};

#define GLL(g, l)                                                            \
  __builtin_amdgcn_global_load_lds(                                          \
      (const __attribute__((address_space(1))) void*)(g),                    \
      (__attribute__((address_space(3))) void*)(l), 16, 0, 0)

__global__ __launch_bounds__(256, 2) void dist_argmin_kernel(
    const u16* __restrict__ zhi, const u16* __restrict__ zlo,
    const u16* __restrict__ cbhi, const u16* __restrict__ cblo,
    const float* __restrict__ e2, int* __restrict__ out_idx,
    int* __restrict__ fb_cnt, int* __restrict__ fb_list) {
  __shared__ union SMem {
    StageMem st;
    RedMem   rd;
  } sm;

  const int tid  = threadIdx.x;
  const int lane = tid & 63;
  const int wid  = tid >> 6;
  const int wr   = wid >> 1;            // wave row (0..1): rows wr*64..
  const int wc   = wid & 1;             // wave col (0..1): codes wc*64..
  const int lr   = lane & 15;           // A-row / B-col within 16x16 tile
  const int kg   = lane >> 4;           // k-group (8 k's each)
  const int row0 = blockIdx.x * BM;
  const int sw   = (lr >> 1) & 3;       // frag-read swizzle (row>>1)&3

  const u16* zhiB = zhi + (size_t)row0 * CDIM;
  const u16* zloB = zlo + (size_t)row0 * CDIM;

  float bv1[16], bv2[16];
  int   bi1[16];
#pragma unroll
  for (int i = 0; i < 16; i++) {
    bv1[i] = __builtin_inff(); bv2[i] = __builtin_inff(); bi1[i] = 0;
  }

  for (int ch = 0; ch < NCH; ch++) {
    const int code0 = ch * 128;
    const u16* bhB = cbhi + (size_t)code0 * CDIM;
    const u16* blB = cblo + (size_t)code0 * CDIM;

    f32x4 acc[4][4];
#pragma unroll
    for (int a = 0; a < 4; a++)
#pragma unroll
      for (int b = 0; b < 4; b++) acc[a][b] = (f32x4){0.f, 0.f, 0.f, 0.f};

    for (int ph = 0; ph < 4; ph++) {
      const int kc = ph * 64;
      __syncthreads();
      // stage 4 arrays, each 1024 slots of 16B; LDS dest linear in slot,
      // global source picks k-quarter q = pos ^ ((row>>1)&3)  (inverse swz)
#pragma unroll
      for (int rr = 0; rr < 4; rr++) {
        int s   = tid + rr * 256;
        int sub = s >> 9;
        int s9  = s & 511;
        int row = s9 >> 2, pos = s9 & 3;
        int q   = pos ^ ((row >> 1) & 3);
        size_t ko = (size_t)(kc + sub * 32 + q * 8);
        GLL(zhiB + (size_t)row * CDIM + ko, &sm.st.ah[sub][row][pos * 8]);
        GLL(zloB + (size_t)row * CDIM + ko, &sm.st.al[sub][row][pos * 8]);
        GLL(bhB  + (size_t)row * CDIM + ko, &sm.st.bh[sub][row][pos * 8]);
        GLL(blB  + (size_t)row * CDIM + ko, &sm.st.bl[sub][row][pos * 8]);
      }
      __syncthreads();

      const int pos = kg ^ sw;
#pragma unroll
      for (int sub = 0; sub < 2; sub++) {
        s16x8 zah[4], zal[4], ebh[4], ebl[4];
#pragma unroll
        for (int t = 0; t < 4; t++) {
          zah[t] = *(const s16x8*)&sm.st.ah[sub][lr + 16 * t + 0][pos * 8];
          zal[t] = *(const s16x8*)&sm.st.al[sub][lr + 16 * t + 0][pos * 8];
          ebh[t] = *(const s16x8*)&sm.st.bh[sub][lr + 16 * t + 0][pos * 8];
          ebl[t] = *(const s16x8*)&sm.st.bl[sub][lr + 16 * t + 0][pos * 8];
        }
        // note: A rows wr*64.., B cols wc*64.. -> use wave-local tiles:
        // zah[t] must come from rows (wr*64 + t*16), ebh from codes (wc*64+t*16)
        // adjust: reload with wave offsets below (kept simple & explicit)
#pragma unroll
        for (int t = 0; t < 4; t++) {
          zah[t] = *(const s16x8*)&sm.st.ah[sub][wr * 64 + t * 16 + lr][pos * 8];
          zal[t] = *(const s16x8*)&sm.st.al[sub][wr * 64 + t * 16 + lr][pos * 8];
          ebh[t] = *(const s16x8*)&sm.st.bh[sub][wc * 64 + t * 16 + lr][pos * 8];
          ebl[t] = *(const s16x8*)&sm.st.bl[sub][wc * 64 + t * 16 + lr][pos * 8];
        }
#pragma unroll
        for (int tr = 0; tr < 4; tr++)
#pragma unroll
          for (int tc = 0; tc < 4; tc++) {
            acc[tr][tc] = __builtin_amdgcn_mfma_f32_16x16x32_bf16(
                zah[tr], ebh[tc], acc[tr][tc], 0, 0, 0);
            acc[tr][tc] = __builtin_amdgcn_mfma_f32_16x16x32_bf16(
                zah[tr], ebl[tc], acc[tr][tc], 0, 0, 0);
            acc[tr][tc] = __builtin_amdgcn_mfma_f32_16x16x32_bf16(
                zal[tr], ebh[tc], acc[tr][tc], 0, 0, 0);
          }
      }
    }

    // chunk epilogue: screened d = e2 - 2G, fold into lane-local best-2
    float e2c[4];
#pragma unroll
    for (int tc = 0; tc < 4; tc++)
      e2c[tc] = e2[code0 + wc * 64 + tc * 16 + lr];
#pragma unroll
    for (int tr = 0; tr < 4; tr++)
#pragma unroll
      for (int rg = 0; rg < 4; rg++) {
        const int rs = tr * 4 + rg;
#pragma unroll
        for (int tc = 0; tc < 4; tc++) {
          float a = acc[tr][tc][rg];
          float d = e2c[tc] - 2.0f * a;
          int code = code0 + wc * 64 + tc * 16 + lr;
          if (d < bv2[rs]) {
            if (d < bv1[rs]) { bv2[rs] = bv1[rs]; bv1[rs] = d; bi1[rs] = code; }
            else bv2[rs] = d;
          }
        }
      }
  }

  // butterfly best-2 merge across the 16 lanes sharing this row set
#pragma unroll
  for (int rs = 0; rs < 16; rs++) {
#pragma unroll
    for (int m = 1; m <= 8; m <<= 1) {
      float o1 = __shfl_xor(bv1[rs], m);
      float o2 = __shfl_xor(bv2[rs], m);
      int   oi = __shfl_xor(bi1[rs], m);
      float mx = fmaxf(bv1[rs], o1);
      if (o1 < bv1[rs]) { bv1[rs] = o1; bi1[rs] = oi; }
      bv2[rs] = fminf(fminf(bv2[rs], o2), mx);
    }
  }

  __syncthreads();                       // stage mem dead; reuse as RedMem
  if (lr == 0) {
#pragma unroll
    for (int tr = 0; tr < 4; tr++)
#pragma unroll
      for (int rg = 0; rg < 4; rg++) {
        int rs = tr * 4 + rg;
        int r  = wr * 64 + tr * 16 + kg * 4 + rg;
        sm.rd.rv1[r][wc] = bv1[rs];
        sm.rd.rv2[r][wc] = bv2[rs];
        sm.rd.ri1[r][wc] = bi1[rs];
      }
  }
  __syncthreads();
  if (tid < BM) {
    float a1 = sm.rd.rv1[tid][0], b1 = sm.rd.rv1[tid][1];
    float a2 = sm.rd.rv2[tid][0], b2 = sm.rd.rv2[tid][1];
    int   ai = sm.rd.ri1[tid][0], bi = sm.rd.ri1[tid][1];
    float v1 = fminf(a1, b1);
    int   i1 = (b1 < a1) ? bi : ai;
    float v2 = fminf(fminf(a2, b2), fmaxf(a1, b1));
    int n = row0 + tid;
    out_idx[n] = i1;
    if (v2 - v1 <= FBW) {
      int slot = atomicAdd(fb_cnt, 1);
      fb_list[slot] = n;
    }
  }
}

// ---------------------------------------------------------------------------
// bit-exact (numpy semantics) full rescan for flagged rows
// ---------------------------------------------------------------------------
__global__ __launch_bounds__(256) void fallback_kernel(
    const float* __restrict__ z, const float* __restrict__ cb,
    const float* __restrict__ z2, const float* __restrict__ e2,
    const int* __restrict__ fb_cnt, const int* __restrict__ fb_list,
    int* __restrict__ out_idx) {
#pragma clang fp contract(off)
  __shared__ float zrow[CDIM];
  __shared__ float rv[256];
  __shared__ int   ri[256];
  int cnt = *fb_cnt;
  int tid = threadIdx.x;
  for (int q = blockIdx.x; q < cnt; q += gridDim.x) {
    int n = fb_list[q];
    int b = n >> 11, t = n & (TT - 1);
    zrow[tid] = z[(size_t)b * CDIM * TT + (size_t)tid * TT + t];
    __syncthreads();
    float z2n = z2[n];
    const float* cr = cb + (size_t)(tid * 4) * CDIM;
    float acc[4] = {0.f, 0.f, 0.f, 0.f};
    for (int k = 0; k < CDIM; k++) {
      float zk = zrow[k];
      acc[0] = acc[0] + zk * cr[k];
      acc[1] = acc[1] + zk * cr[CDIM + k];
      acc[2] = acc[2] + zk * cr[2 * CDIM + k];
      acc[3] = acc[3] + zk * cr[3 * CDIM + k];
    }
    float bv = __builtin_inff(); int bi = 0;
#pragma unroll
    for (int j = 0; j < 4; j++) {
      int   code = tid * 4 + j;
      float d    = (z2n + e2[code]) - 2.0f * acc[j];
      if (d < bv) { bv = d; bi = code; }
    }
    rv[tid] = bv; ri[tid] = bi;
    __syncthreads();
    for (int s = 128; s > 0; s >>= 1) {
      if (tid < s) {
        float v2v = rv[tid + s]; int i2v = ri[tid + s];
        if (v2v < rv[tid] || (v2v == rv[tid] && i2v < ri[tid])) {
          rv[tid] = v2v; ri[tid] = i2v;
        }
      }
      __syncthreads();
    }
    if (tid == 0) out_idx[n] = ri[0];
    __syncthreads();
  }
}

// ---------------------------------------------------------------------------
// Gather z_q, straight-through output fl(z + fl(zq - z)), loss accumulation
// ---------------------------------------------------------------------------
__global__ __launch_bounds__(256) void zq_loss_kernel(
    const float* __restrict__ z, const float* __restrict__ cb,
    const int* __restrict__ idx, float* __restrict__ zq_out,
    double* __restrict__ loss_acc) {
#pragma clang fp contract(off)
  __shared__ double sh[256];
  double local = 0.0;
  int stride = gridDim.x * blockDim.x;
  for (int i = blockIdx.x * blockDim.x + threadIdx.x; i < NELEM; i += stride) {
    int t = i & (TT - 1);
    int b = i >> 19;
    int c = (i >> 11) & (CDIM - 1);
    int n = (b << 11) | t;
    float zq   = cb[(size_t)idx[n] * CDIM + c];
    float zv   = z[i];
    float diff = zq - zv;
    zq_out[i]  = zv + diff;
    float sq   = diff * diff;
    local += (double)sq;
  }
  sh[threadIdx.x] = local;
  __syncthreads();
  for (int s = 128; s > 0; s >>= 1) {
    if (threadIdx.x < s) sh[threadIdx.x] += sh[threadIdx.x + s];
    __syncthreads();
  }
  if (threadIdx.x == 0) atomicAdd(loss_acc, sh[0]);
}

// one-hot (every element written once) + indices output + histogram
__global__ __launch_bounds__(256) void onehot_kernel(
    const int* __restrict__ idx, float* __restrict__ oh,
    float* __restrict__ idx_out, int* __restrict__ cnt) {
  int row  = blockIdx.x * 4 + (threadIdx.x >> 6);
  int lane = threadIdx.x & 63;
  int k    = idx[row];
  if (lane == 0) {
    idx_out[row] = (float)k;
    atomicAdd(&cnt[k], 1);
  }
  float4* dst = (float4*)(oh + (size_t)row * NE);
#pragma unroll
  for (int i = 0; i < 4; i++) {
    int c4   = i * 64 + lane;
    int base = c4 * 4;
    float4 v = {0.f, 0.f, 0.f, 0.f};
    if (k >= base && k < base + 4) ((float*)&v)[k - base] = 1.0f;
    dst[c4] = v;
  }
}

__global__ __launch_bounds__(1024) void finalize_kernel(
    const int* __restrict__ cnt, const double* __restrict__ loss_acc,
    float* __restrict__ out_loss, float* __restrict__ out_perp) {
#pragma clang fp contract(off)
  __shared__ float sh[1024];
  int t = threadIdx.x;
  float em = (float)cnt[t] / 65536.0f;
  sh[t] = em * logf(em + 1e-10f);
  __syncthreads();
  for (int s = 512; s > 0; s >>= 1) {
    if (t < s) sh[t] += sh[t + s];
    __syncthreads();
  }
  if (t == 0) {
    *out_perp = expf(-sh[0]);
    double m  = *loss_acc / (double)NELEM;
    float mf  = (float)m;
    float bt  = 0.25f * mf;
    *out_loss = mf + bt;
  }
}

// ---------------------------------------------------------------------------
extern "C" void kernel_launch(void* const* d_in, const int* in_sizes, int n_in,
                              void* d_out, int out_size, void* d_ws,
                              size_t ws_size, hipStream_t stream) {
  const float* z  = (const float*)d_in[0];
  const float* cb = (const float*)d_in[1];
  float* out = (float*)d_out;

  // workspace layout (small buffers only)
  int*    ws_idx   = (int*)d_ws;                 // 65536 ints
  int*    ws_cnt   = ws_idx + NROWS;             // 1024 ints
  int*    ws_fbcnt = ws_cnt + NE;                // 1 int
  int*    ws_pad   = ws_fbcnt + 1;               // 1 int (align)
  double* ws_loss  = (double*)(ws_pad + 1);      // 1 double
  float*  ws_e2    = (float*)(ws_loss + 1);      // 1024 floats
  float*  ws_z2    = ws_e2 + NE;                 // 65536 floats
  int*    ws_fbl   = (int*)(ws_z2 + NROWS);      // 65536 ints

  // output layout (flat fp32 concat, reference return order)
  float* out_loss = out;
  float* out_zq   = out + 1;
  float* out_perp = out + 1 + (size_t)NELEM;
  float* out_oh   = out + 2 + (size_t)NELEM;
  float* out_idx  = out + 2 + (size_t)NELEM + (size_t)NROWS * NE;

  // bf16 split scratch lives inside the (not yet written) one-hot output
  // region: 2*33.5MB + 2*0.5MB = 68MB << 268MB; onehot overwrites it last.
  uintptr_t sc = ((uintptr_t)out_oh + 63) & ~(uintptr_t)63;
  u16* zhi  = (u16*)sc;
  u16* zlo  = zhi + (size_t)NROWS * CDIM;
  u16* cbhi = zlo + (size_t)NROWS * CDIM;
  u16* cblo = cbhi + (size_t)NE * CDIM;

  hipMemsetAsync(ws_cnt, 0, NE * sizeof(int) + 2 * sizeof(int) + sizeof(double),
                 stream);

  convert_cb_kernel<<<NE * CDIM / 256, 256, 0, stream>>>(cb, cbhi, cblo);
  convert_z_kernel<<<BB * 512, 256, 0, stream>>>(z, zhi, zlo);
  e2_kernel<<<NE / 256, 256, 0, stream>>>(cb, ws_e2);
  z2_kernel<<<NROWS / 256, 256, 0, stream>>>(z, ws_z2);
  dist_argmin_kernel<<<NROWS / BM, 256, 0, stream>>>(
      zhi, zlo, cbhi, cblo, ws_e2, ws_idx, ws_fbcnt, ws_fbl);
  fallback_kernel<<<512, 256, 0, stream>>>(z, cb, ws_z2, ws_e2, ws_fbcnt,
                                           ws_fbl, ws_idx);
  zq_loss_kernel<<<2048, 256, 0, stream>>>(z, cb, ws_idx, out_zq, ws_loss);
  onehot_kernel<<<NROWS / 4, 256, 0, stream>>>(ws_idx, out_oh, out_idx,
                                               ws_cnt);
  finalize_kernel<<<1, 1024, 0, stream>>>(ws_cnt, ws_loss, out_loss, out_perp);
}

// Round 10
// 923.820 us; speedup vs baseline: 1.5707x; 1.3705x over previous
//
#include <hip/hip_runtime.h>

#define BB    32
#define CDIM  256
#define TT    2048
#define NE    1024
#define NROWS (BB * TT)          // 65536
#define NELEM (BB * CDIM * TT)   // 16777216

#define BM   128                 // rows per block
#define NCH  8                   // code chunks of 128 (all 1024 codes/block)

// screening window (r3-proven value): rows with (2nd best - best) <= FBW are
// re-resolved by the bit-exact fallback scan.  2B ~= 1.32e-4 (exact-gap
// quantization 2*ulp(256) + split/order error); 2.5e-4 gives ~1.9x margin.
#define FBW 2.5e-4f

typedef unsigned short u16;
typedef unsigned int   u32;
typedef __attribute__((ext_vector_type(8))) short s16x8;   // 8 bf16
typedef __attribute__((ext_vector_type(4))) float f32x4;

__device__ __forceinline__ u16 f2bf(float f) {
  u32 u = __float_as_uint(f);
  u += 0x7fffu + ((u >> 16) & 1u);     // RNE; no NaN/overflow in our range
  return (u16)(u >> 16);
}

// ---------------------------------------------------------------------------
// numpy pairwise sum of squares over 128 elements (stride in elements).
// fp contract OFF (numpy squares then adds, no FMA).  EXACT path helpers.
// ---------------------------------------------------------------------------
__device__ __forceinline__ float np_sq_sum128(const float* p, int stride) {
#pragma clang fp contract(off)
  float r[8];
#pragma unroll
  for (int j = 0; j < 8; j++) {
    float v = p[(size_t)j * stride];
    r[j] = v * v;
  }
  for (int i = 8; i < 128; i += 8) {
#pragma unroll
    for (int j = 0; j < 8; j++) {
      float v = p[(size_t)(i + j) * stride];
      float s = v * v;
      r[j] += s;
    }
  }
  return ((r[0] + r[1]) + (r[2] + r[3])) + ((r[4] + r[5]) + (r[6] + r[7]));
}

__global__ __launch_bounds__(256) void e2_kernel(const float* __restrict__ cb,
                                                 float* __restrict__ e2) {
#pragma clang fp contract(off)
  int k = blockIdx.x * 256 + threadIdx.x;
  if (k >= NE) return;
  const float* p = cb + (size_t)k * CDIM;
  float h0 = np_sq_sum128(p, 1);
  float h1 = np_sq_sum128(p + 128, 1);
  e2[k] = h0 + h1;
}

__global__ __launch_bounds__(256) void z2_kernel(const float* __restrict__ z,
                                                 float* __restrict__ z2) {
#pragma clang fp contract(off)
  int n = blockIdx.x * 256 + threadIdx.x;
  if (n >= NROWS) return;
  int b = n >> 11;
  int t = n & (TT - 1);
  const float* p = z + (size_t)b * CDIM * TT + t;
  float h0 = np_sq_sum128(p, TT);
  float h1 = np_sq_sum128(p + (size_t)128 * TT, TT);
  z2[n] = h0 + h1;
}

// cb (1024 x 256) -> cbT (256 x 1024) in d_ws, both sides coalesced
__global__ __launch_bounds__(256) void transpose_cb_kernel(
    const float* __restrict__ cb, float* __restrict__ cbT) {
  __shared__ float tile[32][33];
  int tx = threadIdx.x & 31, ty = threadIdx.x >> 5;
  int n0 = blockIdx.x * 32, c0 = blockIdx.y * 32;
#pragma unroll
  for (int i = 0; i < 4; i++)
    tile[ty + 8 * i][tx] = cb[(size_t)(n0 + ty + 8 * i) * CDIM + c0 + tx];
  __syncthreads();
#pragma unroll
  for (int i = 0; i < 4; i++)
    cbT[(size_t)(c0 + ty + 8 * i) * NE + n0 + tx] = tile[tx][ty + 8 * i];
}

// ---------------------------------------------------------------------------
// cb (1024 x 256) fp32 -> cbhi/cblo bf16 (hi + residual), same [code][k] layout
// ---------------------------------------------------------------------------
__global__ __launch_bounds__(256) void convert_cb_kernel(
    const float* __restrict__ cb, u16* __restrict__ cbhi,
    u16* __restrict__ cblo) {
  int i = blockIdx.x * 256 + threadIdx.x;   // grid 1024 -> 262144 elems
  float v  = cb[i];
  u16  h   = f2bf(v);
  float hf = __uint_as_float((u32)h << 16);
  cbhi[i] = h;
  cblo[i] = f2bf(v - hf);
}

// ---------------------------------------------------------------------------
// z (B, C, T) fp32 -> zhi/zlo bf16, row-major [(b,t)][c]   (tiled transpose)
// ---------------------------------------------------------------------------
__global__ __launch_bounds__(256) void convert_z_kernel(
    const float* __restrict__ z, u16* __restrict__ zhi,
    u16* __restrict__ zlo) {
  __shared__ float tile[32][33];
  int bx = blockIdx.x;              // 32 b * 8 c-tiles * 64 t-tiles = 16384
  int b  = bx >> 9;
  int r  = bx & 511;
  int c0 = (r >> 6) << 5;
  int t0 = (r & 63) << 5;
  int tx = threadIdx.x & 31, ty = threadIdx.x >> 5;
#pragma unroll
  for (int i = 0; i < 4; i++) {
    int c = c0 + ty + 8 * i;
    tile[ty + 8 * i][tx] = z[((size_t)b * CDIM + c) * TT + t0 + tx];
  }
  __syncthreads();
#pragma unroll
  for (int i = 0; i < 4; i++) {
    int tl = ty + 8 * i;
    size_t n = (size_t)b * TT + t0 + tl;
    float v  = tile[tx][tl];
    u16  h   = f2bf(v);
    float hf = __uint_as_float((u32)h << 16);
    zhi[n * CDIM + c0 + tx] = h;
    zlo[n * CDIM + c0 + tx] = f2bf(v - hf);
  }
}

// ---------------------------------------------------------------------------
// Distance screen + argmin: bf16-split MFMA GEMM (passed r3 AND post-timing).
// G = zhi*chi + zhi*clo + zlo*chi; screened d = e2[c] - 2G.
// ---------------------------------------------------------------------------
struct StageMem {                       // 64 KiB
  u16 ah[2][128][32];                   // zhi  [plane][row][k]
  u16 al[2][128][32];                   // zlo
  u16 bh[2][128][32];                   // cbhi [plane][code][k]
  u16 bl[2][128][32];                   // cblo
};
struct RedMem {
  float rv1[BM][2];
  float rv2[BM][2];
  int   ri1[BM][2];
};

#define GLL(g, l)                                                            \
  __builtin_amdgcn_global_load_lds(                                          \
      (const __attribute__((address_space(1))) void*)(g),                    \
      (__attribute__((address_space(3))) void*)(l), 16, 0, 0)

__global__ __launch_bounds__(256, 2) void dist_argmin_kernel(
    const u16* __restrict__ zhi, const u16* __restrict__ zlo,
    const u16* __restrict__ cbhi, const u16* __restrict__ cblo,
    const float* __restrict__ e2, int* __restrict__ out_idx,
    int* __restrict__ fb_cnt, int* __restrict__ fb_list) {
  __shared__ union SMem {
    StageMem st;
    RedMem   rd;
  } sm;

  const int tid  = threadIdx.x;
  const int lane = tid & 63;
  const int wid  = tid >> 6;
  const int wr   = wid >> 1;            // wave row (0..1): rows wr*64..
  const int wc   = wid & 1;             // wave col (0..1): codes wc*64..
  const int lr   = lane & 15;           // A-row / B-col within 16x16 tile
  const int kg   = lane >> 4;           // k-group (8 k's each)
  const int row0 = blockIdx.x * BM;
  const int sw   = (lr >> 1) & 3;       // frag-read swizzle (row>>1)&3

  const u16* zhiB = zhi + (size_t)row0 * CDIM;
  const u16* zloB = zlo + (size_t)row0 * CDIM;

  float bv1[16], bv2[16];
  int   bi1[16];
#pragma unroll
  for (int i = 0; i < 16; i++) {
    bv1[i] = __builtin_inff(); bv2[i] = __builtin_inff(); bi1[i] = 0;
  }

  for (int ch = 0; ch < NCH; ch++) {
    const int code0 = ch * 128;
    const u16* bhB = cbhi + (size_t)code0 * CDIM;
    const u16* blB = cblo + (size_t)code0 * CDIM;

    f32x4 acc[4][4];
#pragma unroll
    for (int a = 0; a < 4; a++)
#pragma unroll
      for (int b = 0; b < 4; b++) acc[a][b] = (f32x4){0.f, 0.f, 0.f, 0.f};

    for (int ph = 0; ph < 4; ph++) {
      const int kc = ph * 64;
      __syncthreads();
      // stage 4 arrays, each 1024 slots of 16B; LDS dest linear in slot,
      // global source picks k-quarter q = pos ^ ((row>>1)&3)  (inverse swz)
#pragma unroll
      for (int rr = 0; rr < 4; rr++) {
        int s   = tid + rr * 256;
        int sub = s >> 9;
        int s9  = s & 511;
        int row = s9 >> 2, pos = s9 & 3;
        int q   = pos ^ ((row >> 1) & 3);
        size_t ko = (size_t)(kc + sub * 32 + q * 8);
        GLL(zhiB + (size_t)row * CDIM + ko, &sm.st.ah[sub][row][pos * 8]);
        GLL(zloB + (size_t)row * CDIM + ko, &sm.st.al[sub][row][pos * 8]);
        GLL(bhB  + (size_t)row * CDIM + ko, &sm.st.bh[sub][row][pos * 8]);
        GLL(blB  + (size_t)row * CDIM + ko, &sm.st.bl[sub][row][pos * 8]);
      }
      __syncthreads();

      const int pos = kg ^ sw;
#pragma unroll
      for (int sub = 0; sub < 2; sub++) {
        s16x8 zah[4], zal[4], ebh[4], ebl[4];
#pragma unroll
        for (int t = 0; t < 4; t++) {
          zah[t] = *(const s16x8*)&sm.st.ah[sub][wr * 64 + t * 16 + lr][pos * 8];
          zal[t] = *(const s16x8*)&sm.st.al[sub][wr * 64 + t * 16 + lr][pos * 8];
          ebh[t] = *(const s16x8*)&sm.st.bh[sub][wc * 64 + t * 16 + lr][pos * 8];
          ebl[t] = *(const s16x8*)&sm.st.bl[sub][wc * 64 + t * 16 + lr][pos * 8];
        }
#pragma unroll
        for (int tr = 0; tr < 4; tr++)
#pragma unroll
          for (int tc = 0; tc < 4; tc++) {
            acc[tr][tc] = __builtin_amdgcn_mfma_f32_16x16x32_bf16(
                zah[tr], ebh[tc], acc[tr][tc], 0, 0, 0);
            acc[tr][tc] = __builtin_amdgcn_mfma_f32_16x16x32_bf16(
                zah[tr], ebl[tc], acc[tr][tc], 0, 0, 0);
            acc[tr][tc] = __builtin_amdgcn_mfma_f32_16x16x32_bf16(
                zal[tr], ebh[tc], acc[tr][tc], 0, 0, 0);
          }
      }
    }

    // chunk epilogue: screened d = e2 - 2G, fold into lane-local best-2
    float e2c[4];
#pragma unroll
    for (int tc = 0; tc < 4; tc++)
      e2c[tc] = e2[code0 + wc * 64 + tc * 16 + lr];
#pragma unroll
    for (int tr = 0; tr < 4; tr++)
#pragma unroll
      for (int rg = 0; rg < 4; rg++) {
        const int rs = tr * 4 + rg;
#pragma unroll
        for (int tc = 0; tc < 4; tc++) {
          float a = acc[tr][tc][rg];
          float d = e2c[tc] - 2.0f * a;
          int code = code0 + wc * 64 + tc * 16 + lr;
          if (d < bv2[rs]) {
            if (d < bv1[rs]) { bv2[rs] = bv1[rs]; bv1[rs] = d; bi1[rs] = code; }
            else bv2[rs] = d;
          }
        }
      }
  }

  // butterfly best-2 merge across the 16 lanes sharing this row set
#pragma unroll
  for (int rs = 0; rs < 16; rs++) {
#pragma unroll
    for (int m = 1; m <= 8; m <<= 1) {
      float o1 = __shfl_xor(bv1[rs], m);
      float o2 = __shfl_xor(bv2[rs], m);
      int   oi = __shfl_xor(bi1[rs], m);
      float mx = fmaxf(bv1[rs], o1);
      if (o1 < bv1[rs]) { bv1[rs] = o1; bi1[rs] = oi; }
      bv2[rs] = fminf(fminf(bv2[rs], o2), mx);
    }
  }

  __syncthreads();                       // stage mem dead; reuse as RedMem
  if (lr == 0) {
#pragma unroll
    for (int tr = 0; tr < 4; tr++)
#pragma unroll
      for (int rg = 0; rg < 4; rg++) {
        int rs = tr * 4 + rg;
        int r  = wr * 64 + tr * 16 + kg * 4 + rg;
        sm.rd.rv1[r][wc] = bv1[rs];
        sm.rd.rv2[r][wc] = bv2[rs];
        sm.rd.ri1[r][wc] = bi1[rs];
      }
  }
  __syncthreads();
  if (tid < BM) {
    float a1 = sm.rd.rv1[tid][0], b1 = sm.rd.rv1[tid][1];
    float a2 = sm.rd.rv2[tid][0], b2 = sm.rd.rv2[tid][1];
    int   ai = sm.rd.ri1[tid][0], bi = sm.rd.ri1[tid][1];
    float v1 = fminf(a1, b1);
    int   i1 = (b1 < a1) ? bi : ai;
    float v2 = fminf(fminf(a2, b2), fmaxf(a1, b1));
    int n = row0 + tid;
    out_idx[n] = i1;
    if (v2 - v1 <= FBW) {
      int slot = atomicAdd(fb_cnt, 1);
      fb_list[slot] = n;
    }
  }
}

// ---------------------------------------------------------------------------
// bit-exact (numpy semantics) full rescan for flagged rows.
// zrow staged from strided z (as in the r3-passed version); codebook side
// coalesced via cbT in d_ws: per k, lanes read consecutive codes.
// 4 waves x 64 lanes x 4 codes/lane = 1024 codes; each code is a strictly
// sequential k=0..255 mul-then-add fp32 chain (reference order).
// ---------------------------------------------------------------------------
__global__ __launch_bounds__(256) void fallback_kernel(
    const float* __restrict__ z, const float* __restrict__ cbT,
    const float* __restrict__ z2, const float* __restrict__ e2,
    const int* __restrict__ fb_cnt, const int* __restrict__ fb_list,
    int* __restrict__ out_idx) {
#pragma clang fp contract(off)
  __shared__ float zrow[CDIM];
  __shared__ float rv[4];
  __shared__ int   ri[4];
  const int cnt  = *fb_cnt;
  const int tid  = threadIdx.x;
  const int lane = tid & 63;
  const int w    = tid >> 6;
  for (int q = blockIdx.x; q < cnt; q += gridDim.x) {
    const int n = fb_list[q];
    const int b = n >> 11, t = n & (TT - 1);
    __syncthreads();                       // zrow/rv reuse barrier
    zrow[tid] = z[((size_t)b * CDIM + tid) * TT + t];
    __syncthreads();
    const float z2n = z2[n];
    const int   c0  = w * 256 + lane;      // lane's first code
    const float* ct = cbT + c0;
    float acc0 = 0.f, acc1 = 0.f, acc2 = 0.f, acc3 = 0.f;
    for (int k = 0; k < CDIM; k++) {
      float zk = zrow[k];
      const float* p = ct + (size_t)k * NE;
      acc0 = acc0 + zk * p[0];
      acc1 = acc1 + zk * p[64];
      acc2 = acc2 + zk * p[128];
      acc3 = acc3 + zk * p[192];
    }
    float bv = __builtin_inff(); int bi = 0;
    float dd;
    dd = (z2n + e2[c0 +   0]) - 2.0f * acc0; if (dd < bv) { bv = dd; bi = c0; }
    dd = (z2n + e2[c0 +  64]) - 2.0f * acc1; if (dd < bv) { bv = dd; bi = c0 + 64; }
    dd = (z2n + e2[c0 + 128]) - 2.0f * acc2; if (dd < bv) { bv = dd; bi = c0 + 128; }
    dd = (z2n + e2[c0 + 192]) - 2.0f * acc3; if (dd < bv) { bv = dd; bi = c0 + 192; }
    // wave-level (value, min-index-on-tie) reduce: first-occurrence semantics
#pragma unroll
    for (int m = 1; m < 64; m <<= 1) {
      float ov = __shfl_xor(bv, m);
      int   oi = __shfl_xor(bi, m);
      if (ov < bv || (ov == bv && oi < bi)) { bv = ov; bi = oi; }
    }
    if (lane == 0) { rv[w] = bv; ri[w] = bi; }
    __syncthreads();
    if (tid == 0) {
      float v = rv[0]; int i = ri[0];
#pragma unroll
      for (int x = 1; x < 4; x++)
        if (rv[x] < v || (rv[x] == v && ri[x] < i)) { v = rv[x]; i = ri[x]; }
      out_idx[n] = i;
    }
  }
}

// ---------------------------------------------------------------------------
// Gather z_q, straight-through output fl(z + fl(zq - z)), loss accumulation
// ---------------------------------------------------------------------------
__global__ __launch_bounds__(256) void zq_loss_kernel(
    const float* __restrict__ z, const float* __restrict__ cb,
    const int* __restrict__ idx, float* __restrict__ zq_out,
    double* __restrict__ loss_acc) {
#pragma clang fp contract(off)
  __shared__ double sh[256];
  double local = 0.0;
  int stride = gridDim.x * blockDim.x;
  for (int i = blockIdx.x * blockDim.x + threadIdx.x; i < NELEM; i += stride) {
    int t = i & (TT - 1);
    int b = i >> 19;
    int c = (i >> 11) & (CDIM - 1);
    int n = (b << 11) | t;
    float zq   = cb[(size_t)idx[n] * CDIM + c];
    float zv   = z[i];
    float diff = zq - zv;
    zq_out[i]  = zv + diff;
    float sq   = diff * diff;
    local += (double)sq;
  }
  sh[threadIdx.x] = local;
  __syncthreads();
  for (int s = 128; s > 0; s >>= 1) {
    if (threadIdx.x < s) sh[threadIdx.x] += sh[threadIdx.x + s];
    __syncthreads();
  }
  if (threadIdx.x == 0) atomicAdd(loss_acc, sh[0]);
}

// one-hot (every element written once) + indices output + histogram
__global__ __launch_bounds__(256) void onehot_kernel(
    const int* __restrict__ idx, float* __restrict__ oh,
    float* __restrict__ idx_out, int* __restrict__ cnt) {
  int row  = blockIdx.x * 4 + (threadIdx.x >> 6);
  int lane = threadIdx.x & 63;
  int k    = idx[row];
  if (lane == 0) {
    idx_out[row] = (float)k;
    atomicAdd(&cnt[k], 1);
  }
  float4* dst = (float4*)(oh + (size_t)row * NE);
#pragma unroll
  for (int i = 0; i < 4; i++) {
    int c4   = i * 64 + lane;
    int base = c4 * 4;
    float4 v = {0.f, 0.f, 0.f, 0.f};
    if (k >= base && k < base + 4) ((float*)&v)[k - base] = 1.0f;
    dst[c4] = v;
  }
}

__global__ __launch_bounds__(1024) void finalize_kernel(
    const int* __restrict__ cnt, const double* __restrict__ loss_acc,
    float* __restrict__ out_loss, float* __restrict__ out_perp) {
#pragma clang fp contract(off)
  __shared__ float sh[1024];
  int t = threadIdx.x;
  float em = (float)cnt[t] / 65536.0f;
  sh[t] = em * logf(em + 1e-10f);
  __syncthreads();
  for (int s = 512; s > 0; s >>= 1) {
    if (t < s) sh[t] += sh[t + s];
    __syncthreads();
  }
  if (t == 0) {
    *out_perp = expf(-sh[0]);
    double m  = *loss_acc / (double)NELEM;
    float mf  = (float)m;
    float bt  = 0.25f * mf;
    *out_loss = mf + bt;
  }
}

// ---------------------------------------------------------------------------
extern "C" void kernel_launch(void* const* d_in, const int* in_sizes, int n_in,
                              void* d_out, int out_size, void* d_ws,
                              size_t ws_size, hipStream_t stream) {
  const float* z  = (const float*)d_in[0];
  const float* cb = (const float*)d_in[1];
  float* out = (float*)d_out;

  // workspace layout (total ~1.8 MB; r2 bench proved >= 2.31 MB available)
  int*    ws_idx   = (int*)d_ws;                 // 65536 ints
  int*    ws_cnt   = ws_idx + NROWS;             // 1024 ints
  int*    ws_fbcnt = ws_cnt + NE;                // 1 int
  int*    ws_pad   = ws_fbcnt + 1;               // 1 int (align)
  double* ws_loss  = (double*)(ws_pad + 1);      // 1 double
  float*  ws_e2    = (float*)(ws_loss + 1);      // 1024 floats
  float*  ws_z2    = ws_e2 + NE;                 // 65536 floats
  int*    ws_fbl   = (int*)(ws_z2 + NROWS);      // 65536 ints
  float*  ws_cbT   = (float*)(ws_fbl + NROWS);   // 262144 floats (1 MB)

  // output layout (flat fp32 concat, reference return order)
  float* out_loss = out;
  float* out_zq   = out + 1;
  float* out_perp = out + 1 + (size_t)NELEM;
  float* out_oh   = out + 2 + (size_t)NELEM;
  float* out_idx  = out + 2 + (size_t)NELEM + (size_t)NROWS * NE;

  // bf16-split scratch inside the (not yet written) one-hot output region —
  // EXACTLY the r3-proven 68 MB footprint (no zT, no cbT here).
  uintptr_t sc = ((uintptr_t)out_oh + 63) & ~(uintptr_t)63;
  u16*   zhi  = (u16*)sc;
  u16*   zlo  = zhi + (size_t)NROWS * CDIM;
  u16*   cbhi = zlo + (size_t)NROWS * CDIM;
  u16*   cblo = cbhi + (size_t)NE * CDIM;

  hipMemsetAsync(ws_cnt, 0, NE * sizeof(int) + 2 * sizeof(int) + sizeof(double),
                 stream);

  transpose_cb_kernel<<<dim3(NE / 32, CDIM / 32), 256, 0, stream>>>(cb, ws_cbT);
  convert_cb_kernel<<<NE * CDIM / 256, 256, 0, stream>>>(cb, cbhi, cblo);
  convert_z_kernel<<<BB * 512, 256, 0, stream>>>(z, zhi, zlo);
  e2_kernel<<<NE / 256, 256, 0, stream>>>(cb, ws_e2);
  z2_kernel<<<NROWS / 256, 256, 0, stream>>>(z, ws_z2);
  dist_argmin_kernel<<<NROWS / BM, 256, 0, stream>>>(
      zhi, zlo, cbhi, cblo, ws_e2, ws_idx, ws_fbcnt, ws_fbl);
  fallback_kernel<<<2048, 256, 0, stream>>>(z, ws_cbT, ws_z2, ws_e2, ws_fbcnt,
                                            ws_fbl, ws_idx);
  zq_loss_kernel<<<2048, 256, 0, stream>>>(z, cb, ws_idx, out_zq, ws_loss);
  onehot_kernel<<<NROWS / 4, 256, 0, stream>>>(ws_idx, out_oh, out_idx,
                                               ws_cnt);
  finalize_kernel<<<1, 1024, 0, stream>>>(ws_cnt, ws_loss, out_loss, out_perp);
}